// Round 4
// baseline (523.805 us; speedup 1.0000x reference)
//
#include <hip/hip_runtime.h>
#include <utility>

typedef float f32x2 __attribute__((ext_vector_type(2)));

#define LOG2E 1.44269504088896340736f

__device__ __forceinline__ float rcp_fast(float x) { return __builtin_amdgcn_rcpf(x); }
__device__ __forceinline__ f32x2 mk2(float a, float b) { f32x2 v; v[0] = a; v[1] = b; return v; }
__device__ __forceinline__ f32x2 splat2(float a) { f32x2 v; v[0] = a; v[1] = a; return v; }

__device__ __forceinline__ float sigmoid_fast(float x) {
    return rcp_fast(1.0f + __builtin_amdgcn_exp2f(-LOG2E * x));
}
__device__ __forceinline__ float tanh_fast(float x) {
    float a = __builtin_fabsf(x);
    float t = __builtin_amdgcn_exp2f(-2.0f * LOG2E * a);
    float r = (1.0f - t) * rcp_fast(1.0f + t);
    return __builtin_copysignf(r, x);
}

// DPP rotate within 16-lane rows (verified correct in R2/R3 via self-calibration)
template <int R>
__device__ __forceinline__ int ror16_i(int v) {
    if constexpr (R == 0) return v;
    else return __builtin_amdgcn_update_dpp(v, v, 0x120 + R, 0xF, 0xF, false);
}
template <int R>
__device__ __forceinline__ float ror16(float v) {
    return __builtin_bit_cast(float, ror16_i<R>(__builtin_bit_cast(int, v)));
}

template <typename F, int... Rs>
__device__ __forceinline__ void sf_impl(F&& f, std::integer_sequence<int, Rs...>) {
    (f(std::integral_constant<int, Rs>{}), ...);
}
template <int N, typename F>
__device__ __forceinline__ void static_for(F&& f) {
    sf_impl(f, std::make_integer_sequence<int, N>{});
}

// One wave = 4 batch elements (16 lanes each; lane j = hidden/state index).
// Zero LDS, zero barriers. Per step, two shared DPP rotation sets:
//   rotations of x feed {LN sum, LN sumsq, A.x (fused LN+W_in+W_ih)}
//   rotations of h feed {W_hh.h for next step, W_out.h}
// Gate math: gates = inv*(A.x - mu*u) + d + W_hh.h, with
//   A = W_ih * (W_in * diag(ln_gamma)),  u = A * ones,
//   d = W_ih*(b_in + W_in*ln_beta) + b_ih + b_hh.
// All per-lane weights stored in rotation order (kr[] self-calibrated).
__global__ __launch_bounds__(64, 2) void vm_kernel(
    const float* __restrict__ init_state,  // (B,1,12)
    const float* __restrict__ commands,    // (B,T,4)
    const float* __restrict__ ln_g,        // (16)
    const float* __restrict__ ln_b,        // (16)
    const float* __restrict__ W_in,        // (16,16)
    const float* __restrict__ b_in,        // (16)
    const float* __restrict__ W_ih,        // (64,16)
    const float* __restrict__ W_hh,        // (64,16)
    const float* __restrict__ b_ih,        // (64)
    const float* __restrict__ b_hh,        // (64)
    const float* __restrict__ W_out,       // (12,16)
    const float* __restrict__ b_out,       // (12)
    float* __restrict__ out,               // (B,T,12)
    int B, int T)
{
    const int lane = threadIdx.x;
    const int j = lane & 15;
    const int b = blockIdx.x * 4 + (lane >> 4);

    // ---- calibrate rotation source indices: kr[r] = lane index ror:r reads ----
    int kr[16];
    kr[0] = j;
    static_for<15>([&](auto rc) {
        constexpr int R = decltype(rc)::value + 1;
        kr[R] = ror16_i<R>(j);
    });

    // ---- preamble: W_ih rows for this lane's 4 gate rows (i,f,g,o) ----
    float wi0[16], wi1[16], wi2[16], wi3[16];
#pragma unroll
    for (int m = 0; m < 16; ++m) {
        wi0[m] = W_ih[(0 * 16 + j) * 16 + m];
        wi1[m] = W_ih[(1 * 16 + j) * 16 + m];
        wi2[m] = W_ih[(2 * 16 + j) * 16 + m];
        wi3[m] = W_ih[(3 * 16 + j) * 16 + m];
    }

    // fused A (rotation order) + W_hh (rotation order) + W_out (rotation order)
    f32x2 A01[16], A23[16], Wh01[16], Wh23[16];
    float Wo[16];
    static_for<16>([&](auto rc) {
        constexpr int R = decltype(rc)::value;
        int k = kr[R];
        float gk = ln_g[k];
        f32x2 a01 = splat2(0.0f), a23 = splat2(0.0f);
#pragma unroll
        for (int m = 0; m < 16; ++m) {
            float w = W_in[m * 16 + k] * gk;
            a01 += mk2(wi0[m], wi1[m]) * splat2(w);
            a23 += mk2(wi2[m], wi3[m]) * splat2(w);
        }
        A01[R] = a01;
        A23[R] = a23;
        Wh01[R] = mk2(W_hh[(0 * 16 + j) * 16 + k], W_hh[(1 * 16 + j) * 16 + k]);
        Wh23[R] = mk2(W_hh[(2 * 16 + j) * 16 + k], W_hh[(3 * 16 + j) * 16 + k]);
        Wo[R] = (j < 12) ? W_out[j * 16 + k] : 0.0f;
    });

    // u = A * ones  (kr is a permutation of 0..15, so sum over R = sum over k)
    f32x2 u01 = splat2(0.0f), u23 = splat2(0.0f);
    static_for<16>([&](auto rc) {
        constexpr int R = decltype(rc)::value;
        u01 += A01[R];
        u23 += A23[R];
    });

    // d = W_ih*(b_in + W_in*ln_beta) + b_ih + b_hh
    f32x2 d01 = mk2(b_ih[0 * 16 + j] + b_hh[0 * 16 + j], b_ih[1 * 16 + j] + b_hh[1 * 16 + j]);
    f32x2 d23 = mk2(b_ih[2 * 16 + j] + b_hh[2 * 16 + j], b_ih[3 * 16 + j] + b_hh[3 * 16 + j]);
#pragma unroll
    for (int m = 0; m < 16; ++m) {
        float wb = b_in[m];
#pragma unroll
        for (int k = 0; k < 16; ++k) wb += W_in[m * 16 + k] * ln_b[k];
        d01 += mk2(wi0[m], wi1[m]) * splat2(wb);
        d23 += mk2(wi2[m], wi3[m]) * splat2(wb);
    }

    const float bo = (j < 12) ? b_out[j] : 0.0f;

    // sincos partner (pairs (1,2),(3,4),(5,6)); DPP direction self-calibrated
    int pj = j;
    if (j >= 1 && j <= 6) pj = ((j - 1) ^ 1) + 1;
    const bool donorm = (j >= 1 && j <= 6);
    const bool use_r1 = (kr[1] == pj);

    // ---- recurrent state ----
    const bool is_state = (j < 12);
    float st = is_state ? init_state[b * 12 + j] : 0.0f;
    float c = 0.0f, h = 0.0f;
    f32x2 dH01 = splat2(0.0f), dH23 = splat2(0.0f);  // W_hh . h_{t-1}

    const float* cmd_ptr = commands + (size_t)b * T * 4 + (j - 12);
    float cmd = (j >= 12) ? cmd_ptr[0] : 0.0f;
    float* out_ptr = out + (size_t)b * T * 12 + j;

    for (int t = 0; t < T; ++t) {
        float x = is_state ? st : cmd;

        // prefetch next command (independent of this step's math)
        int tn = (t + 1 < T) ? (t + 1) : t;
        float cmd_next = (j >= 12) ? cmd_ptr[(size_t)tn * 4] : 0.0f;

        // ---- x-phase: one rotation set feeds LN stats and A.x ----
        float sum = x;
        float sumsq = x * x;
        f32x2 dA01 = A01[0] * splat2(x);
        f32x2 dA23 = A23[0] * splat2(x);
        static_for<15>([&](auto rc) {
            constexpr int R = decltype(rc)::value + 1;
            float xr = ror16<R>(x);
            sum += xr;
            sumsq = __builtin_fmaf(xr, xr, sumsq);
            f32x2 xs = splat2(xr);
            dA01 += A01[R] * xs;
            dA23 += A23[R] * xs;
        });
        float mu = sum * 0.0625f;
        float var = __builtin_fmaf(sumsq, 0.0625f, -mu * mu);
        float inv = __builtin_amdgcn_rsqf(var + 1e-5f);

        // gates = inv*(A.x - mu*u) + d + W_hh.h
        f32x2 G01 = (dA01 - splat2(mu) * u01) * splat2(inv) + (d01 + dH01);
        f32x2 G23 = (dA23 - splat2(mu) * u23) * splat2(inv) + (d23 + dH23);

        float iv = sigmoid_fast(G01[0]);
        float fv = sigmoid_fast(G01[1]);
        float gv = tanh_fast(G23[0]);
        float ov = sigmoid_fast(G23[1]);
        c = __builtin_fmaf(fv, c, iv * gv);
        h = ov * tanh_fast(c);

        // ---- h-phase: one rotation set feeds W_hh.h (next step) and W_out.h ----
        f32x2 nH01 = Wh01[0] * splat2(h);
        f32x2 nH23 = Wh23[0] * splat2(h);
        float o = Wo[0] * h;
        static_for<15>([&](auto rc) {
            constexpr int R = decltype(rc)::value + 1;
            float hr = ror16<R>(h);
            f32x2 hs = splat2(hr);
            nH01 += Wh01[R] * hs;
            nH23 += Wh23[R] * hs;
            o = __builtin_fmaf(Wo[R], hr, o);
        });
        dH01 = nH01;
        dH23 = nH23;

        if (is_state) st += o + bo;

        // sincos pair renorm via DPP neighbor exchange
        float p1 = ror16<1>(st);
        float p15 = ror16<15>(st);
        float pv = use_r1 ? p1 : p15;
        float n = __builtin_amdgcn_sqrtf(__builtin_fmaf(st, st, pv * pv)) + 1e-8f;
        float stn = st * rcp_fast(n);
        st = donorm ? stn : st;

        if (is_state) out_ptr[0] = st;
        out_ptr += 12;
        cmd = cmd_next;
    }
}

extern "C" void kernel_launch(void* const* d_in, const int* in_sizes, int n_in,
                              void* d_out, int out_size, void* d_ws, size_t ws_size,
                              hipStream_t stream) {
    const float* init_state = (const float*)d_in[0];
    const float* commands   = (const float*)d_in[1];
    const float* ln_g       = (const float*)d_in[2];
    const float* ln_b       = (const float*)d_in[3];
    const float* W_in       = (const float*)d_in[4];
    const float* b_in       = (const float*)d_in[5];
    const float* W_ih       = (const float*)d_in[6];
    const float* W_hh       = (const float*)d_in[7];
    const float* b_ih       = (const float*)d_in[8];
    const float* b_hh       = (const float*)d_in[9];
    const float* W_out      = (const float*)d_in[10];
    const float* b_out      = (const float*)d_in[11];

    int B = in_sizes[0] / 12;           // 8192
    int T = in_sizes[1] / (B * 4);      // 256

    int blocks = B / 4;                 // 4 batch elements per 64-thread wave
    vm_kernel<<<blocks, 64, 0, stream>>>(init_state, commands, ln_g, ln_b,
                                         W_in, b_in, W_ih, W_hh, b_ih, b_hh,
                                         W_out, b_out, (float*)d_out, B, T);
}